// Round 1
// baseline (598.649 us; speedup 1.0000x reference)
//
#include <hip/hip_runtime.h>
#include <hip/hip_bf16.h>

#define SLOPE 0.1f

// ---- ws float-index layout (flag is an int at float index 0) ----
#define OFF_QE    16      // 900  question_embeds f32
#define OFF_QC    916     // 900  q_conv f32
#define OFF_QW    1816    // 30   q_weights (softmax)
#define OFF_QNI   1846    // 30   ||question_embeds[q]||
#define OFF_QNS   1876    // 30   ||q_conv[q]||
#define OFF_W1    1906    // 2700 conv1_w f32
#define OFF_B1    4606    // 30
#define OFF_W2    4636    // 2700 conv2_w f32
#define OFF_B2    7336    // 30
#define OFF_LQ1W  7366    // 48
#define OFF_LQ1B  7414    // 8
#define OFF_LQ2W  7422    // 8
#define OFF_LQ2B  7430    // 1
#define OFF_SOW   7431    // 4
#define OFF_SOB   7435    // 1
#define OFF_FLW   7436    // 5
#define OFF_FLB   7441    // 1

__device__ __forceinline__ float ldx(const void* p, long i, int bf) {
    if (bf) return __bfloat162float(((const __hip_bfloat16*)p)[i]);
    return ((const float*)p)[i];
}

// ---------------- kernel 0: dtype detection ----------------
// If input is f32, half the u16 words are f32-mantissa noise -> random bf16
// exponent fields. If bf16 (N(0,1) data), exponents stay within [100,134].
__global__ __launch_bounds__(256) void k_detect(const unsigned short* p, int* flag) {
    __shared__ int cnt;
    int tid = threadIdx.x;
    if (tid == 0) cnt = 0;
    __syncthreads();
    int local = 0;
    for (int i = tid; i < 4096; i += 256) {
        unsigned e = (p[i] >> 7) & 0xFFu;
        if (e != 0u && (e < 100u || e > 134u)) local++;
    }
    atomicAdd(&cnt, local);
    __syncthreads();
    if (tid == 0) flag[0] = (cnt > 200) ? 0 : 1;   // 1 = bf16, 0 = f32
}

// ---------------- kernel 1: question path + param conversion ----------------
__global__ __launch_bounds__(256) void k_question(
        const void* qe_in, const void* qidf_in,
        const void* w1_in, const void* b1_in,
        const void* w2_in, const void* b2_in,
        const void* qwW_in, const void* qwb_in,
        const void* lq1W_in, const void* lq1b_in,
        const void* lq2W_in, const void* lq2b_in,
        const void* soW_in, const void* sob_in,
        const void* flW_in, const void* flb_in,
        float* ws) {
    const int tid = threadIdx.x;
    const int bf = ((const int*)ws)[0];
    __shared__ float QE[900], T1[900], QC[900], W[2732], IDF[32], LG[32];

    // convert all small params to f32 in ws
    for (int i = tid; i < 2700; i += 256) ws[OFF_W1 + i] = ldx(w1_in, i, bf);
    for (int i = tid; i < 2700; i += 256) ws[OFF_W2 + i] = ldx(w2_in, i, bf);
    if (tid < 30) { ws[OFF_B1 + tid] = ldx(b1_in, tid, bf);
                    ws[OFF_B2 + tid] = ldx(b2_in, tid, bf); }
    if (tid < 48) ws[OFF_LQ1W + tid] = ldx(lq1W_in, tid, bf);
    if (tid < 8)  { ws[OFF_LQ1B + tid] = ldx(lq1b_in, tid, bf);
                    ws[OFF_LQ2W + tid] = ldx(lq2W_in, tid, bf); }
    if (tid < 4)  ws[OFF_SOW + tid] = ldx(soW_in, tid, bf);
    if (tid < 5)  ws[OFF_FLW + tid] = ldx(flW_in, tid, bf);
    if (tid == 0) { ws[OFF_LQ2B] = ldx(lq2b_in, 0, bf);
                    ws[OFF_SOB]  = ldx(sob_in, 0, bf);
                    ws[OFF_FLB]  = ldx(flb_in, 0, bf); }

    for (int i = tid; i < 900; i += 256) QE[i] = ldx(qe_in, i, bf);
    if (tid < 30) IDF[tid] = ldx(qidf_in, tid, bf);
    for (int i = tid; i < 2700; i += 256) W[i] = ldx(w1_in, i, bf);
    __syncthreads();

    // conv block 1: QE -> T1
    for (int idx = tid; idx < 900; idx += 256) {
        int s = idx / 30, o = idx % 30;
        float acc = ldx(b1_in, o, bf);
        for (int k = 0; k < 3; ++k) {
            int t = s + k - 1;
            if (t < 0 || t >= 30) continue;
            for (int i = 0; i < 30; ++i) acc += QE[t*30 + i] * W[o*90 + i*3 + k];
        }
        acc = acc >= 0.f ? acc : SLOPE * acc;
        T1[idx] = acc + QE[idx];
    }
    __syncthreads();
    for (int i = tid; i < 2700; i += 256) W[i] = ldx(w2_in, i, bf);
    __syncthreads();
    // conv block 2: T1 -> QC
    for (int idx = tid; idx < 900; idx += 256) {
        int s = idx / 30, o = idx % 30;
        float acc = ldx(b2_in, o, bf);
        for (int k = 0; k < 3; ++k) {
            int t = s + k - 1;
            if (t < 0 || t >= 30) continue;
            for (int i = 0; i < 30; ++i) acc += T1[t*30 + i] * W[o*90 + i*3 + k];
        }
        acc = acc >= 0.f ? acc : SLOPE * acc;
        QC[idx] = acc + T1[idx];
    }
    __syncthreads();

    // norms + logits
    if (tid < 30) {
        float s1 = 0.f, s2 = 0.f;
        for (int d = 0; d < 30; ++d) {
            float a = QE[tid*30 + d]; s1 += a*a;
            float b = QC[tid*30 + d]; s2 += b*b;
        }
        ws[OFF_QNI + tid] = sqrtf(s1);
        ws[OFF_QNS + tid] = sqrtf(s2);
        float z = ldx(qwb_in, 0, bf);
        for (int d = 0; d < 30; ++d) z += QC[tid*30 + d] * ldx(qwW_in, d, bf);
        z += IDF[tid] * ldx(qwW_in, 30, bf);
        LG[tid] = z;
    }
    for (int i = tid; i < 900; i += 256) { ws[OFF_QE + i] = QE[i]; ws[OFF_QC + i] = QC[i]; }
    __syncthreads();
    if (tid == 0) {
        float m = -1e30f;
        for (int q = 0; q < 30; ++q) m = fmaxf(m, LG[q]);
        float sum = 0.f, e[30];
        for (int q = 0; q < 30; ++q) { e[q] = expf(LG[q] - m); sum += e[q]; }
        for (int q = 0; q < 30; ++q) ws[OFF_QW + q] = e[q] / sum;
    }
}

// ---------------- kernel 2: per-sentence fused pipeline ----------------
__global__ __launch_bounds__(256) void k_main(const void* doc_in, const void* gaf_in,
                                              void* out, float* ws) {
    const int n = blockIdx.x;
    const int tid = threadIdx.x;
    const int bf = ((const int*)ws)[0];
    __shared__ float A[3000];     // x_orig, later conv_res
    __shared__ float B[3000];     // conv1 output
    __shared__ float C[4096];     // [0..900) q-vecs / [0..2730) weights ; [1024..4024) sims
    __shared__ float xn[100];     // row norms (x, later conv_res)
    __shared__ float FE[30][6];   // pooled features
    __shared__ float red[32];

    // load sentence into A (f32)
    if (bf) {
        const __hip_bfloat16* p = (const __hip_bfloat16*)doc_in + (size_t)n * 3000;
        for (int i = tid; i < 3000; i += 256) A[i] = __bfloat162float(p[i]);
    } else {
        const float* p = (const float*)doc_in + (size_t)n * 3000;
        for (int i = tid; i < 3000; i += 256) A[i] = p[i];
    }
    for (int i = tid; i < 900; i += 256) C[i] = ws[OFF_QE + i];
    __syncthreads();

    if (tid < 100) {
        float s = 0.f;
        for (int d = 0; d < 30; ++d) { float a = A[tid*30 + d]; s += a*a; }
        xn[tid] = sqrtf(s);
    }
    __syncthreads();

    // sim_insens[q][s]
    for (int idx = tid; idx < 3000; idx += 256) {
        int q = idx / 100, s = idx % 100;
        float acc = 0.f;
        for (int d = 0; d < 30; ++d) acc += C[q*30 + d] * A[s*30 + d];
        C[1024 + idx] = acc / (ws[OFF_QNI + q] * xn[s]);
    }
    __syncthreads();

    // pool insens + one-hot
    if (tid < 30) {
        float t0=-1e30f,t1=-1e30f,t2=-1e30f,t3=-1e30f,t4=-1e30f; int cnt = 0;
        for (int s = 0; s < 100; ++s) {
            float v = C[1024 + tid*100 + s];
            if (v > 0.999f) cnt++;
            if (v > t4) {
                if (v > t0)      { t4=t3; t3=t2; t2=t1; t1=t0; t0=v; }
                else if (v > t1) { t4=t3; t3=t2; t2=t1; t1=v; }
                else if (v > t2) { t4=t3; t3=t2; t2=v; }
                else if (v > t3) { t4=t3; t3=v; }
                else             { t4=v; }
            }
        }
        FE[tid][0] = cnt > 0 ? 1.f : 0.f;
        FE[tid][1] = (float)(cnt > 5 ? 5 : cnt) * 0.2f;
        FE[tid][2] = t0;
        FE[tid][3] = (t0+t1+t2+t3+t4) * 0.2f;
    }
    __syncthreads();

    // conv1: A -> B
    for (int i = tid; i < 2700; i += 256) C[i] = ws[OFF_W1 + i];
    if (tid < 30) C[2700 + tid] = ws[OFF_B1 + tid];
    __syncthreads();
    if (tid < 100) {
        int s = tid;
        float acc[30];
        for (int o = 0; o < 30; ++o) acc[o] = C[2700 + o];
        for (int k = 0; k < 3; ++k) {
            int t = s + k - 1;
            if (t < 0 || t >= 100) continue;
            for (int i = 0; i < 30; ++i) {
                float xa = A[t*30 + i];
                for (int o = 0; o < 30; ++o) acc[o] += xa * C[o*90 + i*3 + k];
            }
        }
        for (int o = 0; o < 30; ++o) {
            float y = acc[o] >= 0.f ? acc[o] : SLOPE * acc[o];
            B[s*30 + o] = y + A[s*30 + o];
        }
    }
    __syncthreads();

    // conv2: B -> A (conv_res)
    for (int i = tid; i < 2700; i += 256) C[i] = ws[OFF_W2 + i];
    if (tid < 30) C[2700 + tid] = ws[OFF_B2 + tid];
    __syncthreads();
    if (tid < 100) {
        int s = tid;
        float acc[30];
        for (int o = 0; o < 30; ++o) acc[o] = C[2700 + o];
        for (int k = 0; k < 3; ++k) {
            int t = s + k - 1;
            if (t < 0 || t >= 100) continue;
            for (int i = 0; i < 30; ++i) {
                float xa = B[t*30 + i];
                for (int o = 0; o < 30; ++o) acc[o] += xa * C[o*90 + i*3 + k];
            }
        }
        for (int o = 0; o < 30; ++o) {
            float y = acc[o] >= 0.f ? acc[o] : SLOPE * acc[o];
            A[s*30 + o] = y + B[s*30 + o];
        }
    }
    __syncthreads();

    // sim_sens
    for (int i = tid; i < 900; i += 256) C[i] = ws[OFF_QC + i];
    if (tid < 100) {
        float s = 0.f;
        for (int d = 0; d < 30; ++d) { float a = A[tid*30 + d]; s += a*a; }
        xn[tid] = sqrtf(s);
    }
    __syncthreads();
    for (int idx = tid; idx < 3000; idx += 256) {
        int q = idx / 100, s = idx % 100;
        float acc = 0.f;
        for (int d = 0; d < 30; ++d) acc += C[q*30 + d] * A[s*30 + d];
        C[1024 + idx] = acc / (ws[OFF_QNS + q] * xn[s]);
    }
    __syncthreads();
    if (tid < 30) {
        float t0=-1e30f,t1=-1e30f,t2=-1e30f,t3=-1e30f,t4=-1e30f;
        for (int s = 0; s < 100; ++s) {
            float v = C[1024 + tid*100 + s];
            if (v > t4) {
                if (v > t0)      { t4=t3; t3=t2; t2=t1; t1=t0; t0=v; }
                else if (v > t1) { t4=t3; t3=t2; t2=t1; t1=v; }
                else if (v > t2) { t4=t3; t3=t2; t2=v; }
                else if (v > t3) { t4=t3; t3=v; }
                else             { t4=v; }
            }
        }
        FE[tid][4] = t0;
        FE[tid][5] = (t0+t1+t2+t3+t4) * 0.2f;
    }
    __syncthreads();

    // per-q MLP, weighted sum
    if (tid < 30) {
        float lo = ws[OFF_LQ2B];
        for (int j = 0; j < 8; ++j) {
            float h = ws[OFF_LQ1B + j];
            for (int f = 0; f < 6; ++f) h += FE[tid][f] * ws[OFF_LQ1W + j*6 + f];
            h = h >= 0.f ? h : SLOPE * h;
            lo += h * ws[OFF_LQ2W + j];
        }
        red[tid] = lo * ws[OFF_QW + tid];
    }
    __syncthreads();
    if (tid == 0) {
        float emit = 0.f;
        for (int q = 0; q < 30; ++q) emit += red[q];
        emit *= (1.f / 30.f);
        float z = ws[OFF_SOB];
        z += ldx(gaf_in, (long)n*3 + 0, bf) * ws[OFF_SOW + 0];
        z += ldx(gaf_in, (long)n*3 + 1, bf) * ws[OFF_SOW + 1];
        z += ldx(gaf_in, (long)n*3 + 2, bf) * ws[OFF_SOW + 2];
        z += emit * ws[OFF_SOW + 3];
        float sc = 1.f / (1.f + expf(-z));
        if (bf) ((__hip_bfloat16*)out)[1 + n] = __float2bfloat16(sc);
        else    ((float*)out)[1 + n] = sc;
    }
}

// ---------------- kernel 3: doc-level head ----------------
__global__ __launch_bounds__(256) void k_final(const void* docgaf_in, void* out, const float* ws) {
    const int tid = threadIdx.x;
    const int bf = ((const int*)ws)[0];
    __shared__ float red[256];
    float m = -1e30f;
    for (int i = tid; i < 4000; i += 256) {
        float v = bf ? __bfloat162float(((const __hip_bfloat16*)out)[1 + i])
                     : ((const float*)out)[1 + i];
        m = fmaxf(m, v);
    }
    red[tid] = m;
    __syncthreads();
    for (int off = 128; off > 0; off >>= 1) {
        if (tid < off) red[tid] = fmaxf(red[tid], red[tid + off]);
        __syncthreads();
    }
    if (tid == 0) {
        float f = ws[OFF_FLB] + red[0] * ws[OFF_FLW + 0];
        for (int i = 0; i < 4; ++i) f += ldx(docgaf_in, i, bf) * ws[OFF_FLW + 1 + i];
        if (bf) ((__hip_bfloat16*)out)[0] = __float2bfloat16(f);
        else    ((float*)out)[0] = f;
    }
}

extern "C" void kernel_launch(void* const* d_in, const int* in_sizes, int n_in,
                              void* d_out, int out_size, void* d_ws, size_t ws_size,
                              hipStream_t stream) {
    float* ws = (float*)d_ws;
    k_detect<<<1, 256, 0, stream>>>((const unsigned short*)d_in[0], (int*)d_ws);
    k_question<<<1, 256, 0, stream>>>(d_in[2], d_in[3], d_in[5], d_in[6], d_in[7], d_in[8],
                                      d_in[9], d_in[10], d_in[11], d_in[12], d_in[13], d_in[14],
                                      d_in[15], d_in[16], d_in[17], d_in[18], ws);
    k_main<<<4000, 256, 0, stream>>>(d_in[0], d_in[1], d_out, ws);
    k_final<<<1, 256, 0, stream>>>(d_in[4], d_out, ws);
}

// Round 2
// 212.402 us; speedup vs baseline: 2.8185x; 2.8185x over previous
//
#include <hip/hip_runtime.h>
#include <hip/hip_bf16.h>

#define SLOPE 0.1f

// ---- ws float-index layout (flag is an int at float index 0) ----
#define OFF_QW    1816    // 30   q_weights (softmax)
#define OFF_QNI   1846    // 30   1/||question_embeds[q]||
#define OFF_QNS   1876    // 30   1/||q_conv[q]||
#define OFF_B1    4606    // 30
#define OFF_B2    7336    // 30
#define OFF_LQ1W  7366    // 48
#define OFF_LQ1B  7414    // 8
#define OFF_LQ2W  7422    // 8
#define OFF_LQ2B  7430    // 1
#define OFF_SOW   7431    // 4
#define OFF_SOB   7435    // 1
#define OFF_FLW   7436    // 5
#define OFF_FLB   7441    // 1
// ---- bf16 (u16-index) region, starts at byte 32768 ----
#define U16_QEA   16384   // 32 rows x 32  (A-operand QE, zeros at d>=30, q>=30)
#define U16_QCA   17408   // 32 rows x 32  (A-operand QC)
#define U16_WB1   18432   // 32 rows x 96  (B-operand conv1 W[o][kk], kk=k*30+i)
#define U16_WB2   21504   // 32 rows x 96

typedef __attribute__((ext_vector_type(8))) __bf16 bf16x8;
typedef __attribute__((ext_vector_type(4))) float f32x4;

union Frag { uint4 u4; uint u[4]; bf16x8 v; };

__device__ __forceinline__ float bf2f(ushort h) {
    union { uint u; float f; } c; c.u = ((uint)h) << 16; return c.f;
}
__device__ __forceinline__ ushort f2bf(float f) {   // RNE, finite inputs
    union { float f; uint u; } c; c.f = f;
    uint u = c.u;
    return (ushort)((u + 0x7FFFu + ((u >> 16) & 1u)) >> 16);
}
__device__ __forceinline__ float ldx(const void* p, long i, int bf) {
    if (bf) return bf2f(((const ushort*)p)[i]);
    return ((const float*)p)[i];
}

// ---------------- kernel 0: dtype detection ----------------
__global__ __launch_bounds__(256) void k_detect(const unsigned short* p, int* flag) {
    __shared__ int cnt;
    int tid = threadIdx.x;
    if (tid == 0) cnt = 0;
    __syncthreads();
    int local = 0;
    for (int i = tid; i < 4096; i += 256) {
        unsigned e = (p[i] >> 7) & 0xFFu;
        if (e != 0u && (e < 100u || e > 134u)) local++;
    }
    atomicAdd(&cnt, local);
    __syncthreads();
    if (tid == 0) flag[0] = (cnt > 200) ? 0 : 1;   // 1 = bf16, 0 = f32
}

// ---------------- kernel 1: question path + operand repack ----------------
__global__ __launch_bounds__(256) void k_question(
        const void* qe_in, const void* qidf_in,
        const void* w1_in, const void* b1_in,
        const void* w2_in, const void* b2_in,
        const void* qwW_in, const void* qwb_in,
        const void* lq1W_in, const void* lq1b_in,
        const void* lq2W_in, const void* lq2b_in,
        const void* soW_in, const void* sob_in,
        const void* flW_in, const void* flb_in,
        float* ws) {
    const int tid = threadIdx.x;
    const int bf = ((const int*)ws)[0];
    __shared__ float QE[900], T1[900], QC[900], W[2700], IDF[32], LG[32];

    if (tid < 30) { ws[OFF_B1 + tid] = ldx(b1_in, tid, bf);
                    ws[OFF_B2 + tid] = ldx(b2_in, tid, bf); }
    if (tid < 48) ws[OFF_LQ1W + tid] = ldx(lq1W_in, tid, bf);
    if (tid < 8)  { ws[OFF_LQ1B + tid] = ldx(lq1b_in, tid, bf);
                    ws[OFF_LQ2W + tid] = ldx(lq2W_in, tid, bf); }
    if (tid < 4)  ws[OFF_SOW + tid] = ldx(soW_in, tid, bf);
    if (tid < 5)  ws[OFF_FLW + tid] = ldx(flW_in, tid, bf);
    if (tid == 0) { ws[OFF_LQ2B] = ldx(lq2b_in, 0, bf);
                    ws[OFF_SOB]  = ldx(sob_in, 0, bf);
                    ws[OFF_FLB]  = ldx(flb_in, 0, bf); }

    for (int i = tid; i < 900; i += 256) QE[i] = ldx(qe_in, i, bf);
    if (tid < 30) IDF[tid] = ldx(qidf_in, tid, bf);
    for (int i = tid; i < 2700; i += 256) W[i] = ldx(w1_in, i, bf);
    __syncthreads();

    for (int idx = tid; idx < 900; idx += 256) {
        int s = idx / 30, o = idx % 30;
        float acc = ldx(b1_in, o, bf);
        for (int k = 0; k < 3; ++k) {
            int t = s + k - 1;
            if (t < 0 || t >= 30) continue;
            for (int i = 0; i < 30; ++i) acc += QE[t*30 + i] * W[o*90 + i*3 + k];
        }
        acc = acc >= 0.f ? acc : SLOPE * acc;
        T1[idx] = acc + QE[idx];
    }
    __syncthreads();
    for (int i = tid; i < 2700; i += 256) W[i] = ldx(w2_in, i, bf);
    __syncthreads();
    for (int idx = tid; idx < 900; idx += 256) {
        int s = idx / 30, o = idx % 30;
        float acc = ldx(b2_in, o, bf);
        for (int k = 0; k < 3; ++k) {
            int t = s + k - 1;
            if (t < 0 || t >= 30) continue;
            for (int i = 0; i < 30; ++i) acc += T1[t*30 + i] * W[o*90 + i*3 + k];
        }
        acc = acc >= 0.f ? acc : SLOPE * acc;
        QC[idx] = acc + T1[idx];
    }
    __syncthreads();

    if (tid < 30) {
        float s1 = 0.f, s2 = 0.f;
        for (int d = 0; d < 30; ++d) {
            float a = QE[tid*30 + d]; s1 += a*a;
            float b = QC[tid*30 + d]; s2 += b*b;
        }
        ws[OFF_QNI + tid] = 1.0f / sqrtf(s1);
        ws[OFF_QNS + tid] = 1.0f / sqrtf(s2);
        float z = ldx(qwb_in, 0, bf);
        for (int d = 0; d < 30; ++d) z += QC[tid*30 + d] * ldx(qwW_in, d, bf);
        z += IDF[tid] * ldx(qwW_in, 30, bf);
        LG[tid] = z;
    }
    __syncthreads();
    if (tid == 0) {
        float m = -1e30f;
        for (int q = 0; q < 30; ++q) m = fmaxf(m, LG[q]);
        float sum = 0.f, e[30];
        for (int q = 0; q < 30; ++q) { e[q] = expf(LG[q] - m); sum += e[q]; }
        for (int q = 0; q < 30; ++q) ws[OFF_QW + q] = e[q] / sum;
    }

    // ---- repack A-operands (QE, QC) and B-operands (conv weights) to bf16 ----
    ushort* wsu = (ushort*)ws;
    for (int i = tid; i < 1024; i += 256) {
        int q = i >> 5, d = i & 31;
        float ve = (q < 30 && d < 30) ? QE[q*30 + d] : 0.f;
        float vc = (q < 30 && d < 30) ? QC[q*30 + d] : 0.f;
        wsu[U16_QEA + i] = f2bf(ve);
        wsu[U16_QCA + i] = f2bf(vc);
    }
    for (int i = tid; i < 3072; i += 256) {
        int o = i / 96, kk = i % 96;
        float v1 = 0.f, v2 = 0.f;
        if (o < 30 && kk < 90) {
            int ii = kk % 30, k = kk / 30;
            v1 = ldx(w1_in, o*90 + ii*3 + k, bf);
            v2 = ldx(w2_in, o*90 + ii*3 + k, bf);
        }
        wsu[U16_WB1 + i] = f2bf(v1);
        wsu[U16_WB2 + i] = f2bf(v2);
    }
}

// ---------------- MFMA tile helpers ----------------
// conv GEMM: M=s(100,7 tiles), N=o(30,2 tiles), K=96(3 steps).
// src flat bf16 stride 30, 103 rows (row 0 and rows 101,102 zero). A[s][kk]=src[s*30+kk].
__device__ __forceinline__ void conv_tile(const uint* src32, const uint4* wb,
                                          const float* bias, int t, int l15, int quad) {
    const ushort* srcU = (const ushort*)src32;
    int mt = t >> 1, nt = t & 1;
    int sa = mt * 16 + l15;
    f32x4 acc = {0.f, 0.f, 0.f, 0.f};
    Frag a, b;
    for (int k = 0; k < 3; ++k) {
        if (sa < 100) {
            int base = sa * 15 + k * 16 + quad * 4;
            a.u[0] = src32[base];     a.u[1] = src32[base + 1];
            a.u[2] = src32[base + 2]; a.u[3] = src32[base + 3];
        } else { a.u[0] = a.u[1] = a.u[2] = a.u[3] = 0u; }
        b.u4 = wb[(nt * 16 + l15) * 12 + k * 4 + quad];
        acc = __builtin_amdgcn_mfma_f32_16x16x32_bf16(a.v, b.v, acc, 0, 0, 0);
    }
    int o = nt * 16 + l15;
    // defer writes to caller via epilogue here (dst passed via global pointer trick):
    // done inline by caller-specific wrapper below
    // (kept in one function: write through the dst pointer)
    (void)o; (void)srcU; (void)bias; (void)acc; // no-op placeholder (unused path)
}

// full conv tile with epilogue writing dst
__device__ __forceinline__ void conv_tile_rw(const uint* src32, uint* dst32, const uint4* wb,
                                             const float* bias, int t, int l15, int quad) {
    const ushort* srcU = (const ushort*)src32;
    ushort* dstU = (ushort*)dst32;
    int mt = t >> 1, nt = t & 1;
    int sa = mt * 16 + l15;
    f32x4 acc = {0.f, 0.f, 0.f, 0.f};
    Frag a, b;
    for (int k = 0; k < 3; ++k) {
        if (sa < 100) {
            int base = sa * 15 + k * 16 + quad * 4;
            a.u[0] = src32[base];     a.u[1] = src32[base + 1];
            a.u[2] = src32[base + 2]; a.u[3] = src32[base + 3];
        } else { a.u[0] = a.u[1] = a.u[2] = a.u[3] = 0u; }
        b.u4 = wb[(nt * 16 + l15) * 12 + k * 4 + quad];
        acc = __builtin_amdgcn_mfma_f32_16x16x32_bf16(a.v, b.v, acc, 0, 0, 0);
    }
    int o = nt * 16 + l15;
    if (o < 30) {
        float bo = bias[o];
        for (int r = 0; r < 4; ++r) {
            int s = mt * 16 + quad * 4 + r;
            if (s < 100) {
                float v = acc[r] + bo;
                v = v >= 0.f ? v : SLOPE * v;
                v += bf2f(srcU[(s + 1) * 30 + o]);
                dstU[(s + 1) * 30 + o] = f2bf(v);
            }
        }
    }
}

// sim GEMM: M=q(30,2 tiles), N=s(100,7 tiles), K=32(1 step).
__device__ __forceinline__ void sim_tile(const uint4* qa, const uint* src32, float* SIMb,
                                         const float* invq, const float* INVX,
                                         int t, int l15, int quad) {
    int mt = t / 7, nt = t % 7;
    Frag a, b;
    a.u4 = qa[(mt * 16 + l15) * 4 + quad];
    int s = nt * 16 + l15;
    if (s < 100) {
        int base = (s + 1) * 15 + quad * 4;
        b.u[0] = src32[base];     b.u[1] = src32[base + 1];
        b.u[2] = src32[base + 2]; b.u[3] = src32[base + 3];
    } else { b.u[0] = b.u[1] = b.u[2] = b.u[3] = 0u; }
    f32x4 acc = {0.f, 0.f, 0.f, 0.f};
    acc = __builtin_amdgcn_mfma_f32_16x16x32_bf16(a.v, b.v, acc, 0, 0, 0);
    if (s < 100) {
        float ix = INVX[s];
        for (int r = 0; r < 4; ++r) {
            int q = mt * 16 + quad * 4 + r;
            if (q < 30) SIMb[q * 101 + s] = acc[r] * invq[q] * ix;
        }
    }
}

// top-5 pool over 100 sims per q; 2 lanes per q within wave 0, shfl-merge.
__device__ __forceinline__ void pool_wave(const float* SIMb, float* fe,
                                          int lane, int fbase, int do_oh) {
    int qr = lane & 31;
    int q = qr < 30 ? qr : 0;
    int half = lane >> 5;
    const float* row = SIMb + q * 101 + half * 50;
    float t0=-1e30f, t1=-1e30f, t2=-1e30f, t3=-1e30f, t4=-1e30f;
    int cnt = 0;
    for (int s = 0; s < 50; ++s) {
        float v = row[s];
        cnt += (v > 0.999f) ? 1 : 0;
        bool b0 = v > t0, b1 = v > t1, b2 = v > t2, b3 = v > t3, b4 = v > t4;
        float n0 = b0 ? v  : t0;
        float n1 = b0 ? t0 : (b1 ? v : t1);
        float n2 = b1 ? t1 : (b2 ? v : t2);
        float n3 = b2 ? t2 : (b3 ? v : t3);
        float n4 = b3 ? t3 : (b4 ? v : t4);
        t0=n0; t1=n1; t2=n2; t3=n3; t4=n4;
    }
    float pv[5];
    pv[0] = __shfl_xor(t0, 32); pv[1] = __shfl_xor(t1, 32); pv[2] = __shfl_xor(t2, 32);
    pv[3] = __shfl_xor(t3, 32); pv[4] = __shfl_xor(t4, 32);
    int pc = __shfl_xor(cnt, 32);
    for (int j = 0; j < 5; ++j) {
        float v = pv[j];
        bool b0 = v > t0, b1 = v > t1, b2 = v > t2, b3 = v > t3, b4 = v > t4;
        float n0 = b0 ? v  : t0;
        float n1 = b0 ? t0 : (b1 ? v : t1);
        float n2 = b1 ? t1 : (b2 ? v : t2);
        float n3 = b2 ? t2 : (b3 ? v : t3);
        float n4 = b3 ? t3 : (b4 ? v : t4);
        t0=n0; t1=n1; t2=n2; t3=n3; t4=n4;
    }
    cnt += pc;
    if (do_oh) {
        fe[0] = cnt > 0 ? 1.f : 0.f;
        fe[1] = (float)(cnt > 5 ? 5 : cnt) * 0.2f;
    }
    fe[fbase]     = t0;
    fe[fbase + 1] = (t0 + t1 + t2 + t3 + t4) * 0.2f;
}

// ---------------- kernel 2: per-sentence fused MFMA pipeline ----------------
__global__ __launch_bounds__(256) void k_main(const void* doc_in, const void* gaf_in,
                                              void* out, float* ws) {
    const int n = blockIdx.x;
    const int tid = threadIdx.x;
    const int bf = ((const int*)ws)[0];
    const int lane = tid & 63;
    const int wid = tid >> 6;
    const int l15 = lane & 15;
    const int quad = lane >> 4;

    __shared__ uint XA32[1546];     // X flat bf16: 103 rows x 30 (rows 0,101,102 zero)
    __shared__ uint XB32[1546];     // conv1 output, same layout
    __shared__ float SIM[3030];     // [30][101]
    __shared__ float INVX[100];
    __shared__ float RED[32];

    ushort* XAu = (ushort*)XA32;
    const ushort* wsu = (const ushort*)ws;
    const uint4* qeA = (const uint4*)(wsu + U16_QEA);
    const uint4* qcA = (const uint4*)(wsu + U16_QCA);
    const uint4* wb1 = (const uint4*)(wsu + U16_WB1);
    const uint4* wb2 = (const uint4*)(wsu + U16_WB2);

    // zero pad rows (dwords [0,15) and [1515,1546) in both buffers)
    for (int i = tid; i < 15; i += 256) { XA32[i] = 0u; XB32[i] = 0u; }
    for (int i = 1515 + tid; i < 1546; i += 256) { XA32[i] = 0u; XB32[i] = 0u; }
    // load sentence into XA rows 1..100
    if (bf) {
        const uint* g = (const uint*)((const ushort*)doc_in + (size_t)n * 3000);
        for (int i = tid; i < 1500; i += 256) XA32[15 + i] = g[i];
    } else {
        const float* p = (const float*)doc_in + (size_t)n * 3000;
        for (int i = tid; i < 3000; i += 256) XAu[30 + i] = f2bf(p[i]);
    }
    __syncthreads();

    // inverse row norms of X
    if (tid < 100) {
        const uint* r = XA32 + (tid + 1) * 15;
        float s = 0.f;
        for (int i = 0; i < 15; ++i) {
            uint u = r[i];
            float lo = __uint_as_float(u << 16);
            float hi = __uint_as_float(u & 0xFFFF0000u);
            s += lo * lo + hi * hi;
        }
        INVX[tid] = 1.f / sqrtf(s);
    }
    __syncthreads();

    // sim_insens
    for (int t = wid; t < 14; t += 4)
        sim_tile(qeA, XA32, SIM, ws + OFF_QNI, INVX, t, l15, quad);
    __syncthreads();

    float fe[6];
    // wave0: pool insens (+one-hot); waves 1-3: conv1 XA->XB
    if (wid == 0) {
        pool_wave(SIM, fe, lane, 2, 1);
    } else {
        for (int t = wid - 1; t < 14; t += 3)
            conv_tile_rw(XA32, XB32, wb1, ws + OFF_B1, t, l15, quad);
    }
    __syncthreads();

    // conv2 XB->XA (all waves)
    for (int t = wid; t < 14; t += 4)
        conv_tile_rw(XB32, XA32, wb2, ws + OFF_B2, t, l15, quad);
    __syncthreads();

    // inverse row norms of conv_res
    if (tid < 100) {
        const uint* r = XA32 + (tid + 1) * 15;
        float s = 0.f;
        for (int i = 0; i < 15; ++i) {
            uint u = r[i];
            float lo = __uint_as_float(u << 16);
            float hi = __uint_as_float(u & 0xFFFF0000u);
            s += lo * lo + hi * hi;
        }
        INVX[tid] = 1.f / sqrtf(s);
    }
    __syncthreads();

    // sim_sens
    for (int t = wid; t < 14; t += 4)
        sim_tile(qcA, XA32, SIM, ws + OFF_QNS, INVX, t, l15, quad);
    __syncthreads();

    // wave0: pool sens + per-q MLP
    if (wid == 0) {
        pool_wave(SIM, fe, lane, 4, 0);
        if (lane < 30) {
            float lo = ws[OFF_LQ2B];
            for (int j = 0; j < 8; ++j) {
                float h = ws[OFF_LQ1B + j];
                for (int f = 0; f < 6; ++f) h += fe[f] * ws[OFF_LQ1W + j*6 + f];
                h = h >= 0.f ? h : SLOPE * h;
                lo += h * ws[OFF_LQ2W + j];
            }
            RED[lane] = lo * ws[OFF_QW + lane];
        }
    }
    __syncthreads();

    if (tid == 0) {
        float emit = 0.f;
        for (int q = 0; q < 30; ++q) emit += RED[q];
        emit *= (1.f / 30.f);
        float z = ws[OFF_SOB];
        z += ldx(gaf_in, (long)n*3 + 0, bf) * ws[OFF_SOW + 0];
        z += ldx(gaf_in, (long)n*3 + 1, bf) * ws[OFF_SOW + 1];
        z += ldx(gaf_in, (long)n*3 + 2, bf) * ws[OFF_SOW + 2];
        z += emit * ws[OFF_SOW + 3];
        float sc = 1.f / (1.f + expf(-z));
        if (bf) ((__hip_bfloat16*)out)[1 + n] = __float2bfloat16(sc);
        else    ((float*)out)[1 + n] = sc;
    }
}

// ---------------- kernel 3: doc-level head ----------------
__global__ __launch_bounds__(256) void k_final(const void* docgaf_in, void* out, const float* ws) {
    const int tid = threadIdx.x;
    const int bf = ((const int*)ws)[0];
    __shared__ float red[256];
    float m = -1e30f;
    for (int i = tid; i < 4000; i += 256) {
        float v = bf ? __bfloat162float(((const __hip_bfloat16*)out)[1 + i])
                     : ((const float*)out)[1 + i];
        m = fmaxf(m, v);
    }
    red[tid] = m;
    __syncthreads();
    for (int off = 128; off > 0; off >>= 1) {
        if (tid < off) red[tid] = fmaxf(red[tid], red[tid + off]);
        __syncthreads();
    }
    if (tid == 0) {
        float f = ws[OFF_FLB] + red[0] * ws[OFF_FLW + 0];
        for (int i = 0; i < 4; ++i) f += ldx(docgaf_in, i, bf) * ws[OFF_FLW + 1 + i];
        if (bf) ((__hip_bfloat16*)out)[0] = __float2bfloat16(f);
        else    ((float*)out)[0] = f;
    }
}

extern "C" void kernel_launch(void* const* d_in, const int* in_sizes, int n_in,
                              void* d_out, int out_size, void* d_ws, size_t ws_size,
                              hipStream_t stream) {
    float* ws = (float*)d_ws;
    k_detect<<<1, 256, 0, stream>>>((const unsigned short*)d_in[0], (int*)d_ws);
    k_question<<<1, 256, 0, stream>>>(d_in[2], d_in[3], d_in[5], d_in[6], d_in[7], d_in[8],
                                      d_in[9], d_in[10], d_in[11], d_in[12], d_in[13], d_in[14],
                                      d_in[15], d_in[16], d_in[17], d_in[18], ws);
    k_main<<<4000, 256, 0, stream>>>(d_in[0], d_in[1], d_out, ws);
    k_final<<<1, 256, 0, stream>>>(d_in[4], d_out, ws);
}